// Round 1
// baseline (1165.850 us; speedup 1.0000x reference)
//
#include <hip/hip_runtime.h>

// ITPLConv fused to a single 3x3 conv:
//   out = conv2d_pad1(x, W2),
//   W2[o,c,kh,kw] = sum_d P[o,d]*dw[d]*W[d,c,kh,kw]
//                   - (kh==0&&kw==0) * sum_d P[o,d]*dw[d]*sum_t W[d,c,t]
// Shapes: x (16,128,128,128) f32, W (128,128,3,3), dw (128), P (128,128)
// out (16,128,128,128) f32.

#define CB 32  // channel chunk staged in LDS

// ---- tiny precompute: W2[c][t][o] (o contiguous for coalesced broadcast loads)
__global__ void fuse_weights_kernel(const float* __restrict__ W,
                                    const float* __restrict__ dw,
                                    const float* __restrict__ P,
                                    float* __restrict__ W2) {
    const int c = blockIdx.x;   // input channel 0..127
    const int o = threadIdx.x;  // output channel 0..127
    float acc[9];
#pragma unroll
    for (int t = 0; t < 9; ++t) acc[t] = 0.f;
    for (int d = 0; d < 128; ++d) {
        const float s = P[o * 128 + d] * dw[d];
        const float* wp = W + (size_t)(d * 128 + c) * 9;
        float tsum = 0.f;
#pragma unroll
        for (int t = 0; t < 9; ++t) {
            const float wv = wp[t];
            acc[t] = fmaf(s, wv, acc[t]);
            tsum += wv;
        }
        // corner-tap correction (the "- corr" term lands on kh=0,kw=0)
        acc[0] = fmaf(-s, tsum, acc[0]);
    }
#pragma unroll
    for (int t = 0; t < 9; ++t)
        W2[(c * 9 + t) * 128 + o] = acc[t];
}

// ---- main conv: block = (one n, one h row) -> 128 o x 128 w
// 256 threads: pg = tid&15 (8-wide w group), og = tid>>4 (8-wide o group)
// each thread: acc[8 o][8 w]
__global__ __launch_bounds__(256) void itpl_conv_kernel(const float* __restrict__ x,
                                                        const float* __restrict__ W2,
                                                        float* __restrict__ out) {
    __shared__ float xs[CB][3][132];  // [c][row r=h-1..h+1][j], j=w_in+1, 0..129 valid

    const int h = blockIdx.x;
    const int n = blockIdx.y;
    const int tid = (int)threadIdx.x;
    const int pg = tid & 15;   // w0 = 8*pg
    const int og = tid >> 4;   // o0 = 8*og

    float acc[8][8];
#pragma unroll
    for (int i = 0; i < 8; ++i)
#pragma unroll
        for (int p = 0; p < 8; ++p) acc[i][p] = 0.f;

    for (int c0 = 0; c0 < 128; c0 += CB) {
        __syncthreads();
        // stage CB channels x 3 rows x 128 interior floats (float4 granules)
        for (int g = tid; g < CB * 3 * 32; g += 256) {
            const int f4 = g & 31;
            const int row = g >> 5;          // 0..CB*3-1
            const int r = row % 3;
            const int c = row / 3;
            const int hr = h + r - 1;
            float4 v = make_float4(0.f, 0.f, 0.f, 0.f);
            if ((unsigned)hr < 128u)
                v = *reinterpret_cast<const float4*>(
                    x + ((((size_t)n * 128 + c0 + c) * 128 + hr) * 128 + f4 * 4));
            float* dst = &xs[c][r][1 + f4 * 4];
            dst[0] = v.x; dst[1] = v.y; dst[2] = v.z; dst[3] = v.w;
        }
        if (tid < CB * 3) {  // zero the w=-1 / w=128 pad columns
            const int r = tid % 3;
            const int c = tid / 3;
            xs[c][r][0] = 0.f;
            xs[c][r][129] = 0.f;
        }
        __syncthreads();

        for (int c = 0; c < CB; ++c) {
#pragma unroll
            for (int kh = 0; kh < 3; ++kh) {
                float xr[12];
                const float* xsp = &xs[c][kh][pg * 8];  // 32B-aligned
                *reinterpret_cast<float4*>(&xr[0]) = *reinterpret_cast<const float4*>(xsp);
                *reinterpret_cast<float4*>(&xr[4]) = *reinterpret_cast<const float4*>(xsp + 4);
                *reinterpret_cast<float4*>(&xr[8]) = *reinterpret_cast<const float4*>(xsp + 8);
#pragma unroll
                for (int kw = 0; kw < 3; ++kw) {
                    const float* wp = W2 + (size_t)((c0 + c) * 9 + kh * 3 + kw) * 128 + og * 8;
                    float wv[8];
                    *reinterpret_cast<float4*>(&wv[0]) = *reinterpret_cast<const float4*>(wp);
                    *reinterpret_cast<float4*>(&wv[4]) = *reinterpret_cast<const float4*>(wp + 4);
#pragma unroll
                    for (int i = 0; i < 8; ++i)
#pragma unroll
                        for (int p = 0; p < 8; ++p)
                            acc[i][p] = fmaf(wv[i], xr[p + kw], acc[i][p]);
                }
            }
        }
    }

    // write 8 o x 8 w per thread, float4-coalesced
#pragma unroll
    for (int i = 0; i < 8; ++i) {
        float* op = out + ((((size_t)n * 128 + og * 8 + i) * 128 + h) * 128 + pg * 8);
        *reinterpret_cast<float4*>(op)     = make_float4(acc[i][0], acc[i][1], acc[i][2], acc[i][3]);
        *reinterpret_cast<float4*>(op + 4) = make_float4(acc[i][4], acc[i][5], acc[i][6], acc[i][7]);
    }
}

extern "C" void kernel_launch(void* const* d_in, const int* in_sizes, int n_in,
                              void* d_out, int out_size, void* d_ws, size_t ws_size,
                              hipStream_t stream) {
    const float* x  = (const float*)d_in[0];
    const float* W  = (const float*)d_in[1];   // (128,128,3,3)
    const float* dw = (const float*)d_in[2];   // (128,)
    const float* P  = (const float*)d_in[3];   // (128,128) [o,d]
    float* out = (float*)d_out;
    float* W2  = (float*)d_ws;                 // 128*9*128 floats = 576 KiB

    fuse_weights_kernel<<<128, 128, 0, stream>>>(W, dw, P, W2);
    itpl_conv_kernel<<<dim3(128, 16), 256, 0, stream>>>(x, W2, out);
}

// Round 3
// 420.950 us; speedup vs baseline: 2.7696x; 2.7696x over previous
//
#include <hip/hip_runtime.h>
#include <hip/hip_bf16.h>

// ITPLConv fused to a single 3x3 conv, executed as bf16 implicit-GEMM on MFMA.
//   out = conv2d_pad1(x, W2),
//   W2[o,c,kh,kw] = sum_d P[o,d]*dw[d]*W[d,c,kh,kw]
//                   - (kh==0&&kw==0) * sum_d P[o,d]*dw[d]*sum_t W[d,c,t]
// Pipeline:
//   1) fuse_weights_bf16: W2b[t][o][c] bf16 (c contiguous -> B-frag ds/global reads)
//   2) to_nhwc_bf16: x NCHW f32 -> xb NHWC bf16 (c contiguous -> A-frag reads);
//      also zeros a 32KB "zrow" used as branch-free source for out-of-range h rows
//   3) itpl_mfma_kernel: per block one (n,h) row: 128 spatial x 128 o,
//      K-loop 4 chunks of 32 c x 9 taps, double-buffered LDS staged via
//      global_load_lds(16B) with source-side XOR swizzle (rule 21), bf16 MFMA.
// Fallback: if ws_size < ~67.4MB, run the verified round-1 fp32 path.

typedef __attribute__((ext_vector_type(8))) short bf16x8;
typedef __attribute__((ext_vector_type(4))) float f32x4;

__device__ inline unsigned short f2bf(float f) {  // RNE, finite inputs
    unsigned u = __builtin_bit_cast(unsigned, f);
    return (unsigned short)((u + 0x7FFFu + ((u >> 16) & 1u)) >> 16);
}

__device__ inline void gll16(const void* g, void* l) {
    __builtin_amdgcn_global_load_lds((const __attribute__((address_space(1))) void*)g,
                                     (__attribute__((address_space(3))) void*)l, 16, 0, 0);
}

// ---------------- pass 1: fused weights, bf16, layout [t][o][c] ----------------
__global__ void fuse_weights_bf16(const float* __restrict__ W,
                                  const float* __restrict__ dw,
                                  const float* __restrict__ P,
                                  unsigned short* __restrict__ w2b) {
    const int c = blockIdx.x;   // 0..127
    const int o = threadIdx.x;  // 0..127
    float acc[9];
#pragma unroll
    for (int t = 0; t < 9; ++t) acc[t] = 0.f;
    for (int d = 0; d < 128; ++d) {
        const float s = P[o * 128 + d] * dw[d];
        const float* wp = W + (size_t)(d * 128 + c) * 9;
        float tsum = 0.f;
#pragma unroll
        for (int t = 0; t < 9; ++t) {
            const float wv = wp[t];
            acc[t] = fmaf(s, wv, acc[t]);
            tsum += wv;
        }
        acc[0] = fmaf(-s, tsum, acc[0]);  // corner-tap correction
    }
#pragma unroll
    for (int t = 0; t < 9; ++t)
        w2b[(t * 128 + o) * 128 + c] = f2bf(acc[t]);
}

// ---------------- pass 2: NCHW f32 -> NHWC bf16 (+ zero zrow) ----------------
__global__ __launch_bounds__(256) void to_nhwc_bf16(const float* __restrict__ x,
                                                    unsigned short* __restrict__ xb,
                                                    unsigned short* __restrict__ zrow) {
    __shared__ __attribute__((aligned(16))) unsigned short ys[128 * 130];  // [c][w], pad 130
    const int h = blockIdx.x, n = blockIdx.y, tid = (int)threadIdx.x;

    // stage: coalesced float4 reads along w, packed uint writes into [c][w]
    for (int u = tid; u < 4096; u += 256) {
        const int c = u >> 5, w4 = (u & 31) * 4;
        float4 v = *reinterpret_cast<const float4*>(
            x + ((((size_t)n * 128 + c) * 128 + h) * 128 + w4));
        unsigned p0 = (unsigned)f2bf(v.x) | ((unsigned)f2bf(v.y) << 16);
        unsigned p1 = (unsigned)f2bf(v.z) | ((unsigned)f2bf(v.w) << 16);
        *reinterpret_cast<unsigned*>(&ys[c * 130 + w4]) = p0;
        *reinterpret_cast<unsigned*>(&ys[c * 130 + w4 + 2]) = p1;
    }
    __syncthreads();
    // write out: unit = (w, c-octet); 16 consecutive lanes -> 256B contiguous store
    for (int u = tid; u < 2048; u += 256) {
        const int w = u >> 4, c8 = u & 15;
        bf16x8 st;
#pragma unroll
        for (int j = 0; j < 8; ++j) st[j] = (short)ys[(c8 * 8 + j) * 130 + w];
        *reinterpret_cast<bf16x8*>(
            xb + ((((size_t)n * 128 + h) * 128 + w) * 128 + c8 * 8)) = st;
    }
    // one block zeroes zrow (runs before conv kernel on the same stream)
    if (h == 0 && n == 0) {
        bf16x8 z = 0;
        for (int u = tid; u < 2048; u += 256)
            *reinterpret_cast<bf16x8*>(zrow + u * 8) = z;
    }
}

// ---------------- pass 3: MFMA conv ----------------
// LDS A-tile: [3 rows r][132 wi][32 c] bf16, wi = w+1 (halo wi=0,129 always zero).
// 16B c-quad slots swizzled: LDS slot s holds source c-quad (s ^ ((wi>>1)&3)).
#define LDS_CHUNK (3 * 132 * 32)  // shorts per buffer (25344 B)

__global__ __launch_bounds__(256) void itpl_mfma_kernel(
    const unsigned short* __restrict__ xb,   // NHWC bf16
    const unsigned short* __restrict__ w2b,  // [9][o][c] bf16
    const unsigned short* __restrict__ zrow, // 32KB zeros
    float* __restrict__ out) {
    __shared__ __attribute__((aligned(16))) unsigned short lds[2][LDS_CHUNK];

    // XCD-aware swizzle: consecutive h rows land on the same XCD (share 2/3 of A rows)
    const int bid = (int)blockIdx.x;                 // 0..2047, 2048 % 8 == 0
    const int lin = (bid & 7) * 256 + (bid >> 3);
    const int h = lin & 127, n = lin >> 7;

    const int tid = (int)threadIdx.x;
    const int l = tid & 63, wid = tid >> 6;
    const int wr = wid >> 1, wc = wid & 1;           // wave quadrant: 64 sp x 64 o

    f32x4 acc[4][4];
#pragma unroll
    for (int i = 0; i < 4; ++i)
#pragma unroll
        for (int j = 0; j < 4; ++j) acc[i][j] = {0.f, 0.f, 0.f, 0.f};

    // zero halo rows wi=0 and wi=129 in both buffers (staging never touches them)
    if (tid < 48) {
        const int slot = tid & 3, row = tid >> 2;    // row 0..11
        const int buf = row / 6, rr = row % 6, r = rr >> 1, wi = (rr & 1) ? 129 : 0;
        bf16x8 z = 0;
        *reinterpret_cast<bf16x8*>(&lds[buf][(r * 132 + wi) * 32 + slot * 8]) = z;
    }

    const size_t nbase = (size_t)n * 128;

    auto stage = [&](int buf, int c0) {
        // 24 global_load_lds(16B) per block: s = (row r 0..2) * 8 + (w-segment 0..7)
        for (int s = wid * 6; s < wid * 6 + 6; ++s) {
            const int r = s >> 3, seg = s & 7;
            const int hr = h + r - 1;
            const int wl = seg * 16 + (l >> 2);      // this lane's w
            const int wi = 1 + wl;
            const int q = (l & 3) ^ ((wi >> 1) & 3); // pre-swizzled source c-quad
            const unsigned short* src;
            if ((unsigned)hr < 128u)
                src = xb + (((nbase + hr) * 128 + wl) * 128) + c0 + q * 8;
            else
                src = zrow + (wl * 128 + c0 + q * 8);
            // linear LDS dest: lane0 base; HW adds lane*16B
            gll16(src, (void*)&lds[buf][(r * 132 + 1 + seg * 16) * 32]);
        }
    };

    auto compute = [&](int buf, int c0) {
        const unsigned short* lb = &lds[buf][0];
#pragma unroll
        for (int t = 0; t < 9; ++t) {
            const int r = t / 3, kw = t % 3;
            bf16x8 bfr[4], afr[4];
#pragma unroll
            for (int ni = 0; ni < 4; ++ni) {
                const int o = wc * 64 + ni * 16 + (l & 15);
                bfr[ni] = *reinterpret_cast<const bf16x8*>(
                    w2b + ((t * 128 + o) * 128 + c0 + (l >> 4) * 8));
            }
#pragma unroll
            for (int mi = 0; mi < 4; ++mi) {
                const int wi = 1 + wr * 64 + mi * 16 + (l & 15) + kw - 1;
                const int slot = (l >> 4) ^ ((wi >> 1) & 3);
                afr[mi] = *reinterpret_cast<const bf16x8*>(
                    lb + (r * 132 + wi) * 32 + slot * 8);
            }
#pragma unroll
            for (int mi = 0; mi < 4; ++mi)
#pragma unroll
                for (int ni = 0; ni < 4; ++ni)
                    acc[mi][ni] = __builtin_amdgcn_mfma_f32_16x16x32_bf16(
                        afr[mi], bfr[ni], acc[mi][ni], 0, 0, 0);
        }
    };

    stage(0, 0);
    __syncthreads();
#pragma unroll
    for (int k = 0; k < 4; ++k) {
        if (k < 3) stage((k + 1) & 1, (k + 1) * 32);
        compute(k & 1, k * 32);
        __syncthreads();
    }

    // C-write: lane l reg j -> w = base + (l>>4)*4 + j (float4), o = base + (l&15)
    const size_t ob = (nbase * 128 + h) * 128;       // ((n*128 + o)*128 + h)*128 + w, o added below
#pragma unroll
    for (int mi = 0; mi < 4; ++mi) {
        const int w = wr * 64 + mi * 16 + (l >> 4) * 4;
#pragma unroll
        for (int ni = 0; ni < 4; ++ni) {
            const int o = wc * 64 + ni * 16 + (l & 15);
            *reinterpret_cast<f32x4*>(out + ob + (size_t)o * 128 * 128 + w) = acc[mi][ni];
        }
    }
}

// ---------------- fallback fp32 path (round-1, verified) ----------------
#define CB 32
__global__ void fuse_weights_kernel(const float* __restrict__ W,
                                    const float* __restrict__ dw,
                                    const float* __restrict__ P,
                                    float* __restrict__ W2) {
    const int c = blockIdx.x;
    const int o = threadIdx.x;
    float acc[9];
#pragma unroll
    for (int t = 0; t < 9; ++t) acc[t] = 0.f;
    for (int d = 0; d < 128; ++d) {
        const float s = P[o * 128 + d] * dw[d];
        const float* wp = W + (size_t)(d * 128 + c) * 9;
        float tsum = 0.f;
#pragma unroll
        for (int t = 0; t < 9; ++t) {
            const float wv = wp[t];
            acc[t] = fmaf(s, wv, acc[t]);
            tsum += wv;
        }
        acc[0] = fmaf(-s, tsum, acc[0]);
    }
#pragma unroll
    for (int t = 0; t < 9; ++t) W2[(c * 9 + t) * 128 + o] = acc[t];
}

__global__ __launch_bounds__(256) void itpl_conv_kernel(const float* __restrict__ x,
                                                        const float* __restrict__ W2,
                                                        float* __restrict__ out) {
    __shared__ float xs[CB][3][132];
    const int h = blockIdx.x;
    const int n = blockIdx.y;
    const int tid = (int)threadIdx.x;
    const int pg = tid & 15;
    const int og = tid >> 4;
    float acc[8][8];
#pragma unroll
    for (int i = 0; i < 8; ++i)
#pragma unroll
        for (int p = 0; p < 8; ++p) acc[i][p] = 0.f;
    for (int c0 = 0; c0 < 128; c0 += CB) {
        __syncthreads();
        for (int g = tid; g < CB * 3 * 32; g += 256) {
            const int f4 = g & 31;
            const int row = g >> 5;
            const int r = row % 3;
            const int c = row / 3;
            const int hr = h + r - 1;
            float4 v = make_float4(0.f, 0.f, 0.f, 0.f);
            if ((unsigned)hr < 128u)
                v = *reinterpret_cast<const float4*>(
                    x + ((((size_t)n * 128 + c0 + c) * 128 + hr) * 128 + f4 * 4));
            float* dst = &xs[c][r][1 + f4 * 4];
            dst[0] = v.x; dst[1] = v.y; dst[2] = v.z; dst[3] = v.w;
        }
        if (tid < CB * 3) {
            const int r = tid % 3;
            const int c = tid / 3;
            xs[c][r][0] = 0.f;
            xs[c][r][129] = 0.f;
        }
        __syncthreads();
        for (int c = 0; c < CB; ++c) {
#pragma unroll
            for (int kh = 0; kh < 3; ++kh) {
                float xr[12];
                const float* xsp = &xs[c][kh][pg * 8];
                *reinterpret_cast<float4*>(&xr[0]) = *reinterpret_cast<const float4*>(xsp);
                *reinterpret_cast<float4*>(&xr[4]) = *reinterpret_cast<const float4*>(xsp + 4);
                *reinterpret_cast<float4*>(&xr[8]) = *reinterpret_cast<const float4*>(xsp + 8);
#pragma unroll
                for (int kw = 0; kw < 3; ++kw) {
                    const float* wp = W2 + (size_t)((c0 + c) * 9 + kh * 3 + kw) * 128 + og * 8;
                    float wv[8];
                    *reinterpret_cast<float4*>(&wv[0]) = *reinterpret_cast<const float4*>(wp);
                    *reinterpret_cast<float4*>(&wv[4]) = *reinterpret_cast<const float4*>(wp + 4);
#pragma unroll
                    for (int i = 0; i < 8; ++i)
#pragma unroll
                        for (int p = 0; p < 8; ++p)
                            acc[i][p] = fmaf(wv[i], xr[p + kw], acc[i][p]);
                }
            }
        }
    }
#pragma unroll
    for (int i = 0; i < 8; ++i) {
        float* op = out + ((((size_t)n * 128 + og * 8 + i) * 128 + h) * 128 + pg * 8);
        *reinterpret_cast<float4*>(op)     = make_float4(acc[i][0], acc[i][1], acc[i][2], acc[i][3]);
        *reinterpret_cast<float4*>(op + 4) = make_float4(acc[i][4], acc[i][5], acc[i][6], acc[i][7]);
    }
}

extern "C" void kernel_launch(void* const* d_in, const int* in_sizes, int n_in,
                              void* d_out, int out_size, void* d_ws, size_t ws_size,
                              hipStream_t stream) {
    const float* x  = (const float*)d_in[0];
    const float* W  = (const float*)d_in[1];
    const float* dw = (const float*)d_in[2];
    const float* P  = (const float*)d_in[3];
    float* out = (float*)d_out;

    const size_t XB_BYTES = 67108864ull;   // 16*128*128*128 bf16
    const size_t ZR_BYTES = 32768ull;      // one zeroed NHWC row
    const size_t W2B_BYTES = 294912ull;    // 9*128*128 bf16
    if (ws_size >= XB_BYTES + ZR_BYTES + W2B_BYTES) {
        unsigned short* xbw  = (unsigned short*)d_ws;
        unsigned short* zrow = (unsigned short*)((char*)d_ws + XB_BYTES);
        unsigned short* w2b  = (unsigned short*)((char*)d_ws + XB_BYTES + ZR_BYTES);
        fuse_weights_bf16<<<128, 128, 0, stream>>>(W, dw, P, w2b);
        to_nhwc_bf16<<<dim3(128, 16), 256, 0, stream>>>(x, xbw, zrow);
        itpl_mfma_kernel<<<2048, 256, 0, stream>>>(xbw, w2b, zrow, out);
    } else {
        float* W2 = (float*)d_ws;
        fuse_weights_kernel<<<128, 128, 0, stream>>>(W, dw, P, W2);
        itpl_conv_kernel<<<dim3(128, 16), 256, 0, stream>>>(x, W2, out);
    }
}

// Round 4
// 413.155 us; speedup vs baseline: 2.8218x; 1.0189x over previous
//
#include <hip/hip_runtime.h>
#include <hip/hip_bf16.h>

// ITPLConv fused to a single 3x3 conv, executed as bf16 implicit-GEMM on MFMA.
//   out = conv2d_pad1(x, W2),
//   W2[o,c,kh,kw] = sum_d P[o,d]*dw[d]*W[d,c,kh,kw]
//                   - (kh==0&&kw==0) * sum_d P[o,d]*dw[d]*sum_t W[d,c,t]
// R4 changes vs R3:
//   - to_nhwc_bf16: per-lane 4c x 4w register micro-transpose, uint2 LDS writes,
//     aligned b128 LDS reads + coalesced 256B stores (was: 8 scalar ds_read_u16/store)
//   - itpl_mfma_kernel: B-fragments (w2b) loaded in per-kh-row batches of 12 before
//     the MFMA loop (was: per-tap in-loop -> latency serialization, MfmaUtil 17.7%)

typedef __attribute__((ext_vector_type(8))) short bf16x8;
typedef __attribute__((ext_vector_type(4))) float f32x4;
typedef __attribute__((ext_vector_type(2))) unsigned int u32x2;

__device__ inline unsigned short f2bf(float f) {  // RNE, finite inputs
    unsigned u = __builtin_bit_cast(unsigned, f);
    return (unsigned short)((u + 0x7FFFu + ((u >> 16) & 1u)) >> 16);
}

__device__ inline void gll16(const void* g, void* l) {
    __builtin_amdgcn_global_load_lds((const __attribute__((address_space(1))) void*)g,
                                     (__attribute__((address_space(3))) void*)l, 16, 0, 0);
}

// ---------------- pass 1: fused weights, bf16, layout [t][o][c] ----------------
__global__ void fuse_weights_bf16(const float* __restrict__ W,
                                  const float* __restrict__ dw,
                                  const float* __restrict__ P,
                                  unsigned short* __restrict__ w2b) {
    const int c = blockIdx.x;   // 0..127
    const int o = threadIdx.x;  // 0..127
    float acc[9];
#pragma unroll
    for (int t = 0; t < 9; ++t) acc[t] = 0.f;
    for (int d = 0; d < 128; ++d) {
        const float s = P[o * 128 + d] * dw[d];
        const float* wp = W + (size_t)(d * 128 + c) * 9;
        float tsum = 0.f;
#pragma unroll
        for (int t = 0; t < 9; ++t) {
            const float wv = wp[t];
            acc[t] = fmaf(s, wv, acc[t]);
            tsum += wv;
        }
        acc[0] = fmaf(-s, tsum, acc[0]);  // corner-tap correction
    }
#pragma unroll
    for (int t = 0; t < 9; ++t)
        w2b[(t * 128 + o) * 128 + c] = f2bf(acc[t]);
}

// ---------------- pass 2: NCHW f32 -> NHWC bf16 (+ zero zrow) ----------------
// Per block: one (n,h) plane, 128c x 128w.
// Phase 1: lane owns a 4c x 4w tile (4 coalesced float4 reads), register-transposes
//   to 4 c-quads, writes uint2 into LDS [w][c] (row stride 136 shorts = 272B, 16B-aligned).
// Phase 2: aligned b128 reads (16 lanes = one w row's 16 c-octets) -> 256B coalesced stores.
__global__ __launch_bounds__(256) void to_nhwc_bf16(const float* __restrict__ x,
                                                    unsigned short* __restrict__ xb,
                                                    unsigned short* __restrict__ zrow) {
    __shared__ __attribute__((aligned(16))) unsigned ys[128 * 68];  // dwords: [w][c-pair], pad 68
    const int h = blockIdx.x, n = blockIdx.y, tid = (int)threadIdx.x;
    const int wv = tid >> 6, l = tid & 63;

#pragma unroll
    for (int i = 0; i < 4; ++i) {
        const int wh = (i & 1) * 64;
        const int CB0 = (2 * wv + (i >> 1)) * 16;
        const int c0 = CB0 + 4 * (l >> 4);
        const int w0 = wh + 4 * (l & 15);

        float4 v[4];
#pragma unroll
        for (int r = 0; r < 4; ++r)
            v[r] = *reinterpret_cast<const float4*>(
                x + ((((size_t)n * 128 + c0 + r) * 128 + h) * 128 + w0));

        // register transpose: for each of 4 w, pack 4 consecutive c as 2 dwords
        const float* vf = reinterpret_cast<const float*>(v);  // vf[r*4 + j]
#pragma unroll
        for (int j = 0; j < 4; ++j) {
            unsigned u0 = (unsigned)f2bf(vf[0 * 4 + j]) | ((unsigned)f2bf(vf[1 * 4 + j]) << 16);
            unsigned u1 = (unsigned)f2bf(vf[2 * 4 + j]) | ((unsigned)f2bf(vf[3 * 4 + j]) << 16);
            u32x2 st; st[0] = u0; st[1] = u1;
            *reinterpret_cast<u32x2*>(&ys[(w0 + j) * 68 + (c0 >> 1)]) = st;  // 8B-aligned
        }
    }
    __syncthreads();

#pragma unroll
    for (int k = 0; k < 8; ++k) {
        const int u = tid + 256 * k;
        const int c8 = u & 15, w = u >> 4;
        bf16x8 val = *reinterpret_cast<const bf16x8*>(
            reinterpret_cast<const unsigned short*>(ys) + w * 136 + c8 * 8);  // 272B rows -> 16B aligned
        *reinterpret_cast<bf16x8*>(
            xb + ((((size_t)n * 128 + h) * 128 + w) * 128 + c8 * 8)) = val;
    }

    // one block zeroes zrow (runs before conv kernel on the same stream)
    if (h == 0 && n == 0) {
        bf16x8 z = 0;
        for (int u = tid; u < 2048; u += 256)
            *reinterpret_cast<bf16x8*>(zrow + u * 8) = z;
    }
}

// ---------------- pass 3: MFMA conv ----------------
// LDS A-tile: [3 rows r][132 wi][32 c] bf16, wi = w+1 (halo wi=0,129 always zero).
// 16B c-quad slots swizzled: LDS slot s holds source c-quad (s ^ ((wi>>1)&3)).
#define LDS_CHUNK (3 * 132 * 32)  // shorts per buffer (25344 B)

__global__ __launch_bounds__(256, 2) void itpl_mfma_kernel(
    const unsigned short* __restrict__ xb,   // NHWC bf16
    const unsigned short* __restrict__ w2b,  // [9][o][c] bf16
    const unsigned short* __restrict__ zrow, // 32KB zeros
    float* __restrict__ out) {
    __shared__ __attribute__((aligned(16))) unsigned short lds[2][LDS_CHUNK];

    // XCD-aware swizzle: consecutive h rows land on the same XCD (share 2/3 of A rows)
    const int bid = (int)blockIdx.x;                 // 0..2047, 2048 % 8 == 0
    const int lin = (bid & 7) * 256 + (bid >> 3);
    const int h = lin & 127, n = lin >> 7;

    const int tid = (int)threadIdx.x;
    const int l = tid & 63, wid = tid >> 6;
    const int wr = wid >> 1, wc = wid & 1;           // wave quadrant: 64 sp x 64 o

    f32x4 acc[4][4];
#pragma unroll
    for (int i = 0; i < 4; ++i)
#pragma unroll
        for (int j = 0; j < 4; ++j) acc[i][j] = {0.f, 0.f, 0.f, 0.f};

    // zero halo rows wi=0 and wi=129 in both buffers (staging never touches them)
    if (tid < 48) {
        const int slot = tid & 3, row = tid >> 2;    // row 0..11
        const int buf = row / 6, rr = row % 6, r = rr >> 1, wi = (rr & 1) ? 129 : 0;
        bf16x8 z = 0;
        *reinterpret_cast<bf16x8*>(&lds[buf][(r * 132 + wi) * 32 + slot * 8]) = z;
    }

    const size_t nbase = (size_t)n * 128;

    auto stage = [&](int buf, int c0) {
        // 24 global_load_lds(16B) per block: s = (row r 0..2) * 8 + (w-segment 0..7)
        for (int s = wid * 6; s < wid * 6 + 6; ++s) {
            const int r = s >> 3, seg = s & 7;
            const int hr = h + r - 1;
            const int wl = seg * 16 + (l >> 2);      // this lane's w
            const int wi = 1 + wl;
            const int q = (l & 3) ^ ((wi >> 1) & 3); // pre-swizzled source c-quad
            const unsigned short* src;
            if ((unsigned)hr < 128u)
                src = xb + (((nbase + hr) * 128 + wl) * 128) + c0 + q * 8;
            else
                src = zrow + (wl * 128 + c0 + q * 8);
            // linear LDS dest: lane0 base; HW adds lane*16B
            gll16(src, (void*)&lds[buf][(r * 132 + 1 + seg * 16) * 32]);
        }
    };

    auto compute = [&](int buf, int c0) {
        const unsigned short* lb = &lds[buf][0];
#pragma unroll
        for (int r = 0; r < 3; ++r) {
            // batch-load the kh-row's 12 B-fragments first: one latency exposure
            // per 48 MFMAs (was per-tap -> MfmaUtil 17.7%)
            bf16x8 bfr[3][4];
#pragma unroll
            for (int tt = 0; tt < 3; ++tt)
#pragma unroll
                for (int ni = 0; ni < 4; ++ni) {
                    const int t = r * 3 + tt;
                    const int o = wc * 64 + ni * 16 + (l & 15);
                    bfr[tt][ni] = *reinterpret_cast<const bf16x8*>(
                        w2b + ((t * 128 + o) * 128 + c0 + (l >> 4) * 8));
                }
#pragma unroll
            for (int kw = 0; kw < 3; ++kw) {
                bf16x8 afr[4];
#pragma unroll
                for (int mi = 0; mi < 4; ++mi) {
                    const int wi = 1 + wr * 64 + mi * 16 + (l & 15) + kw - 1;
                    const int slot = (l >> 4) ^ ((wi >> 1) & 3);
                    afr[mi] = *reinterpret_cast<const bf16x8*>(
                        lb + (r * 132 + wi) * 32 + slot * 8);
                }
#pragma unroll
                for (int mi = 0; mi < 4; ++mi)
#pragma unroll
                    for (int ni = 0; ni < 4; ++ni)
                        acc[mi][ni] = __builtin_amdgcn_mfma_f32_16x16x32_bf16(
                            afr[mi], bfr[kw][ni], acc[mi][ni], 0, 0, 0);
            }
        }
    };

    stage(0, 0);
    __syncthreads();
#pragma unroll
    for (int k = 0; k < 4; ++k) {
        if (k < 3) stage((k + 1) & 1, (k + 1) * 32);
        compute(k & 1, k * 32);
        __syncthreads();
    }

    // C-write: lane l reg j -> w = base + (l>>4)*4 + j (float4), o = base + (l&15)
    const size_t ob = (nbase * 128 + h) * 128;
#pragma unroll
    for (int mi = 0; mi < 4; ++mi) {
        const int w = wr * 64 + mi * 16 + (l >> 4) * 4;
#pragma unroll
        for (int ni = 0; ni < 4; ++ni) {
            const int o = wc * 64 + ni * 16 + (l & 15);
            *reinterpret_cast<f32x4*>(out + ob + (size_t)o * 128 * 128 + w) = acc[mi][ni];
        }
    }
}

// ---------------- fallback fp32 path (round-1, verified) ----------------
#define CB 32
__global__ void fuse_weights_kernel(const float* __restrict__ W,
                                    const float* __restrict__ dw,
                                    const float* __restrict__ P,
                                    float* __restrict__ W2) {
    const int c = blockIdx.x;
    const int o = threadIdx.x;
    float acc[9];
#pragma unroll
    for (int t = 0; t < 9; ++t) acc[t] = 0.f;
    for (int d = 0; d < 128; ++d) {
        const float s = P[o * 128 + d] * dw[d];
        const float* wp = W + (size_t)(d * 128 + c) * 9;
        float tsum = 0.f;
#pragma unroll
        for (int t = 0; t < 9; ++t) {
            const float wv = wp[t];
            acc[t] = fmaf(s, wv, acc[t]);
            tsum += wv;
        }
        acc[0] = fmaf(-s, tsum, acc[0]);
    }
#pragma unroll
    for (int t = 0; t < 9; ++t) W2[(c * 9 + t) * 128 + o] = acc[t];
}

__global__ __launch_bounds__(256) void itpl_conv_kernel(const float* __restrict__ x,
                                                        const float* __restrict__ W2,
                                                        float* __restrict__ out) {
    __shared__ float xs[CB][3][132];
    const int h = blockIdx.x;
    const int n = blockIdx.y;
    const int tid = (int)threadIdx.x;
    const int pg = tid & 15;
    const int og = tid >> 4;
    float acc[8][8];
#pragma unroll
    for (int i = 0; i < 8; ++i)
#pragma unroll
        for (int p = 0; p < 8; ++p) acc[i][p] = 0.f;
    for (int c0 = 0; c0 < 128; c0 += CB) {
        __syncthreads();
        for (int g = tid; g < CB * 3 * 32; g += 256) {
            const int f4 = g & 31;
            const int row = g >> 5;
            const int r = row % 3;
            const int c = row / 3;
            const int hr = h + r - 1;
            float4 v = make_float4(0.f, 0.f, 0.f, 0.f);
            if ((unsigned)hr < 128u)
                v = *reinterpret_cast<const float4*>(
                    x + ((((size_t)n * 128 + c0 + c) * 128 + hr) * 128 + f4 * 4));
            float* dst = &xs[c][r][1 + f4 * 4];
            dst[0] = v.x; dst[1] = v.y; dst[2] = v.z; dst[3] = v.w;
        }
        if (tid < CB * 3) {
            const int r = tid % 3;
            const int c = tid / 3;
            xs[c][r][0] = 0.f;
            xs[c][r][129] = 0.f;
        }
        __syncthreads();
        for (int c = 0; c < CB; ++c) {
#pragma unroll
            for (int kh = 0; kh < 3; ++kh) {
                float xr[12];
                const float* xsp = &xs[c][kh][pg * 8];
                *reinterpret_cast<float4*>(&xr[0]) = *reinterpret_cast<const float4*>(xsp);
                *reinterpret_cast<float4*>(&xr[4]) = *reinterpret_cast<const float4*>(xsp + 4);
                *reinterpret_cast<float4*>(&xr[8]) = *reinterpret_cast<const float4*>(xsp + 8);
#pragma unroll
                for (int kw = 0; kw < 3; ++kw) {
                    const float* wp = W2 + (size_t)((c0 + c) * 9 + kh * 3 + kw) * 128 + og * 8;
                    float wv[8];
                    *reinterpret_cast<float4*>(&wv[0]) = *reinterpret_cast<const float4*>(wp);
                    *reinterpret_cast<float4*>(&wv[4]) = *reinterpret_cast<const float4*>(wp + 4);
#pragma unroll
                    for (int i = 0; i < 8; ++i)
#pragma unroll
                        for (int p = 0; p < 8; ++p)
                            acc[i][p] = fmaf(wv[i], xr[p + kw], acc[i][p]);
                }
            }
        }
    }
#pragma unroll
    for (int i = 0; i < 8; ++i) {
        float* op = out + ((((size_t)n * 128 + og * 8 + i) * 128 + h) * 128 + pg * 8);
        *reinterpret_cast<float4*>(op)     = make_float4(acc[i][0], acc[i][1], acc[i][2], acc[i][3]);
        *reinterpret_cast<float4*>(op + 4) = make_float4(acc[i][4], acc[i][5], acc[i][6], acc[i][7]);
    }
}

extern "C" void kernel_launch(void* const* d_in, const int* in_sizes, int n_in,
                              void* d_out, int out_size, void* d_ws, size_t ws_size,
                              hipStream_t stream) {
    const float* x  = (const float*)d_in[0];
    const float* W  = (const float*)d_in[1];
    const float* dw = (const float*)d_in[2];
    const float* P  = (const float*)d_in[3];
    float* out = (float*)d_out;

    const size_t XB_BYTES = 67108864ull;   // 16*128*128*128 bf16
    const size_t ZR_BYTES = 32768ull;      // one zeroed NHWC row
    const size_t W2B_BYTES = 294912ull;    // 9*128*128 bf16
    if (ws_size >= XB_BYTES + ZR_BYTES + W2B_BYTES) {
        unsigned short* xbw  = (unsigned short*)d_ws;
        unsigned short* zrow = (unsigned short*)((char*)d_ws + XB_BYTES);
        unsigned short* w2b  = (unsigned short*)((char*)d_ws + XB_BYTES + ZR_BYTES);
        fuse_weights_bf16<<<128, 128, 0, stream>>>(W, dw, P, w2b);
        to_nhwc_bf16<<<dim3(128, 16), 256, 0, stream>>>(x, xbw, zrow);
        itpl_mfma_kernel<<<2048, 256, 0, stream>>>(xbw, w2b, zrow, out);
    } else {
        float* W2 = (float*)d_ws;
        fuse_weights_kernel<<<128, 128, 0, stream>>>(W, dw, P, W2);
        itpl_conv_kernel<<<dim3(128, 16), 256, 0, stream>>>(x, W2, out);
    }
}

// Round 5
// 344.984 us; speedup vs baseline: 3.3794x; 1.1976x over previous
//
#include <hip/hip_runtime.h>

// ITPLConv fused to a single 3x3 conv, executed as bf16 implicit-GEMM on MFMA.
//   out = conv2d_pad1(x, W2),
//   W2[o,c,kh,kw] = sum_d P[o,d]*dw[d]*W[d,c,kh,kw]
//                   - (kh==0&&kw==0) * sum_d P[o,d]*dw[d]*sum_t W[d,c,t]
// R5 changes vs R4:
//   - prep_kernel: fuse + NCHW->NHWC transpose merged into ONE dispatch (2176 blocks);
//     fuse rewritten: W-slice staged in LDS, P-row preloaded to registers (was
//     1152 latency-serial scalar loads/thread on a 128-block grid run serially).
//   - itpl_mfma_kernel: 512 threads (8 waves) per block, same LDS -> 24 waves/CU
//     (was 10); operand-swapped MFMA (D[o][sp]) -> coalesced C-stores; weights
//     re-laid out as w2f[t][g][o][8c] -> B-loads 256B-contiguous per 16 lanes.

typedef __attribute__((ext_vector_type(8))) short bf16x8;
typedef __attribute__((ext_vector_type(4))) float f32x4;
typedef __attribute__((ext_vector_type(2))) unsigned int u32x2;

__device__ inline unsigned short f2bf(float f) {  // RNE, finite inputs
    unsigned u = __builtin_bit_cast(unsigned, f);
    return (unsigned short)((u + 0x7FFFu + ((u >> 16) & 1u)) >> 16);
}

__device__ inline void gll16(const void* g, void* l) {
    __builtin_amdgcn_global_load_lds((const __attribute__((address_space(1))) void*)g,
                                     (__attribute__((address_space(3))) void*)l, 16, 0, 0);
}

// ---------------- pass 1 (merged): transpose blocks [0,2048) + fuse blocks [2048,2176) ----
__global__ __launch_bounds__(256) void prep_kernel(
    const float* __restrict__ x, const float* __restrict__ W,
    const float* __restrict__ dw, const float* __restrict__ P,
    unsigned short* __restrict__ xb, unsigned short* __restrict__ zrow,
    unsigned short* __restrict__ w2f) {
    __shared__ __attribute__((aligned(16))) unsigned smem[128 * 68];  // 34.8 KB
    const int bid = (int)blockIdx.x, tid = (int)threadIdx.x;

    if (bid < 2048) {
        // ---- transpose block: one (n,h) plane, NCHW f32 -> NHWC bf16 ----
        const int h = bid & 127, n = bid >> 7;
        const int wv = tid >> 6, l = tid & 63;
#pragma unroll
        for (int i = 0; i < 4; ++i) {
            const int wh = (i & 1) * 64;
            const int CB0 = (2 * wv + (i >> 1)) * 16;
            const int c0 = CB0 + 4 * (l >> 4);
            const int w0 = wh + 4 * (l & 15);
            float4 v[4];
#pragma unroll
            for (int r = 0; r < 4; ++r)
                v[r] = *reinterpret_cast<const float4*>(
                    x + ((((size_t)n * 128 + c0 + r) * 128 + h) * 128 + w0));
            const float* vf = reinterpret_cast<const float*>(v);  // vf[r*4 + j]
#pragma unroll
            for (int j = 0; j < 4; ++j) {
                unsigned u0 = (unsigned)f2bf(vf[0 * 4 + j]) | ((unsigned)f2bf(vf[1 * 4 + j]) << 16);
                unsigned u1 = (unsigned)f2bf(vf[2 * 4 + j]) | ((unsigned)f2bf(vf[3 * 4 + j]) << 16);
                u32x2 st; st[0] = u0; st[1] = u1;
                *reinterpret_cast<u32x2*>(&smem[(w0 + j) * 68 + (c0 >> 1)]) = st;
            }
        }
        __syncthreads();
#pragma unroll
        for (int k = 0; k < 8; ++k) {
            const int u = tid + 256 * k;
            const int c8 = u & 15, w = u >> 4;
            bf16x8 val = *reinterpret_cast<const bf16x8*>(
                reinterpret_cast<const unsigned short*>(smem) + w * 136 + c8 * 8);
            *reinterpret_cast<bf16x8*>(
                xb + ((((size_t)n * 128 + h) * 128 + w) * 128 + c8 * 8)) = val;
        }
        if (h == 0 && n == 0) {  // zero zrow once
            bf16x8 z = 0;
            for (int u = tid; u < 2048; u += 256)
                *reinterpret_cast<bf16x8*>(zrow + u * 8) = z;
        }
    } else {
        // ---- fuse block: one input channel c; 256 threads = (d-half t8, o) ----
        const int c = bid - 2048;
        float* Wl  = reinterpret_cast<float*>(smem);         // [128 d][9 t]
        float* red = reinterpret_cast<float*>(smem) + 1152;  // [128 o][10]
        for (int idx = tid; idx < 1152; idx += 256)
            Wl[idx] = W[(size_t)((idx / 9) * 128 + c) * 9 + (idx % 9)];
        __syncthreads();
        const int t8 = tid >> 7, o = tid & 127;
        // preload this thread's P-row half (o fixed, d contiguous)
        float pr[64];
#pragma unroll
        for (int q = 0; q < 16; ++q)
            *reinterpret_cast<float4*>(&pr[q * 4]) = *reinterpret_cast<const float4*>(
                P + (size_t)o * 128 + t8 * 64 + q * 4);
        float acc[9];
#pragma unroll
        for (int t = 0; t < 9; ++t) acc[t] = 0.f;
        for (int dd = 0; dd < 64; ++dd) {
            const int d = t8 * 64 + dd;
            const float s = pr[dd] * dw[d];
            const float* wp = Wl + d * 9;
            float tsum = 0.f;
#pragma unroll
            for (int t = 0; t < 9; ++t) {
                const float wv2 = wp[t];
                acc[t] = fmaf(s, wv2, acc[t]);
                tsum += wv2;
            }
            acc[0] = fmaf(-s, tsum, acc[0]);  // corner-tap correction
        }
        if (t8 == 1) {
#pragma unroll
            for (int t = 0; t < 9; ++t) red[o * 10 + t] = acc[t];
        }
        __syncthreads();
        if (t8 == 0) {
#pragma unroll
            for (int t = 0; t < 9; ++t) {
                const float v = acc[t] + red[o * 10 + t];
                // w2f[t][g = c>>3][o][c&7]
                w2f[(size_t)((t * 16 + (c >> 3)) * 128 + o) * 8 + (c & 7)] = f2bf(v);
            }
        }
    }
}

// ---------------- pass 2: MFMA conv ----------------
// LDS A-tile: [3 rows r][132 wi][32 c] bf16, wi = w+1 (halo wi=0,129 always zero).
// 16B c-quad slots swizzled: LDS slot s holds source c-quad (s ^ ((wi>>1)&3)).
// 8 waves: ws = wid&3 (32-wide sp quarter), wo = wid>>2 (64-wide o half).
// Operand-swapped MFMA: D[m=o][n=sp] = mfma(w_frag, x_frag, acc).
#define LDS_CHUNK (3 * 132 * 32)  // shorts per buffer (25344 B)

__global__ __launch_bounds__(512, 6) void itpl_mfma_kernel(
    const unsigned short* __restrict__ xb,   // NHWC bf16
    const unsigned short* __restrict__ w2f,  // [9 t][16 g][128 o][8 c] bf16
    const unsigned short* __restrict__ zrow, // 32KB zeros
    float* __restrict__ out) {
    __shared__ __attribute__((aligned(16))) unsigned short lds[2][LDS_CHUNK];

    const int bid = (int)blockIdx.x;                 // 0..2047, 2048 % 8 == 0
    const int lin = (bid & 7) * 256 + (bid >> 3);    // XCD-aware swizzle
    const int h = lin & 127, n = lin >> 7;

    const int tid = (int)threadIdx.x;
    const int l = tid & 63, wid = tid >> 6;
    const int ws = wid & 3, wo = wid >> 2;

    f32x4 acc[4][2];  // [o-frag][sp-frag]
#pragma unroll
    for (int i = 0; i < 4; ++i)
#pragma unroll
        for (int j = 0; j < 2; ++j) acc[i][j] = {0.f, 0.f, 0.f, 0.f};

    // zero halo columns wi=0 and wi=129 in both buffers
    if (tid < 48) {
        const int slot = tid & 3, row = tid >> 2;    // row 0..11
        const int buf = row / 6, rr = row % 6, r = rr >> 1, wi = (rr & 1) ? 129 : 0;
        bf16x8 z = 0;
        *reinterpret_cast<bf16x8*>(&lds[buf][(r * 132 + wi) * 32 + slot * 8]) = z;
    }

    const size_t nbase = (size_t)n * 128;

    auto stage = [&](int buf, int c0) {
        // 24 global_load_lds(16B) per block, 3 per wave
#pragma unroll
        for (int i = 0; i < 3; ++i) {
            const int s = wid * 3 + i;
            const int r = s >> 3, seg = s & 7;
            const int hr = h + r - 1;
            const int wl = seg * 16 + (l >> 2);      // this lane's w
            const int wi = 1 + wl;
            const int q = (l & 3) ^ ((wi >> 1) & 3); // pre-swizzled source c-quad
            const unsigned short* src;
            if ((unsigned)hr < 128u)
                src = xb + (((nbase + hr) * 128 + wl) * 128) + c0 + q * 8;
            else
                src = zrow + (wl * 128 + c0 + q * 8);
            gll16(src, (void*)&lds[buf][(r * 132 + 1 + seg * 16) * 32]);
        }
    };

    auto compute = [&](int buf, int c0) {
        const unsigned short* lb = &lds[buf][0];
        const int g0 = c0 >> 3;
#pragma unroll
        for (int r = 0; r < 3; ++r) {
#pragma unroll
            for (int kw = 0; kw < 3; ++kw) {
                const int t = r * 3 + kw;
                bf16x8 afr[2];
#pragma unroll
                for (int si = 0; si < 2; ++si) {
                    const int wi = 1 + ws * 32 + si * 16 + (l & 15) + kw - 1;
                    const int slot = (l >> 4) ^ ((wi >> 1) & 3);
                    afr[si] = *reinterpret_cast<const bf16x8*>(
                        lb + (r * 132 + wi) * 32 + slot * 8);
                }
                bf16x8 bfr[4];
#pragma unroll
                for (int oi = 0; oi < 4; ++oi) {
                    const int o = wo * 64 + oi * 16 + (l & 15);
                    bfr[oi] = *reinterpret_cast<const bf16x8*>(
                        w2f + (size_t)((t * 16 + g0 + (l >> 4)) * 128 + o) * 8);
                }
#pragma unroll
                for (int oi = 0; oi < 4; ++oi)
#pragma unroll
                    for (int si = 0; si < 2; ++si)
                        acc[oi][si] = __builtin_amdgcn_mfma_f32_16x16x32_bf16(
                            bfr[oi], afr[si], acc[oi][si], 0, 0, 0);
            }
        }
    };

    stage(0, 0);
    __syncthreads();
#pragma unroll
    for (int k = 0; k < 4; ++k) {
        if (k < 3) stage((k + 1) & 1, (k + 1) * 32);
        compute(k & 1, k * 32);
        __syncthreads();
    }

    // C-write: D[m=o][n=sp]: o = base + (l>>4)*4 + j, w = base + (l&15)
    // 16 consecutive lanes -> 64B contiguous per (oi,si,j)
    float* ob = out + nbase * 16384 + (size_t)h * 128;
#pragma unroll
    for (int oi = 0; oi < 4; ++oi) {
        const int o0 = wo * 64 + oi * 16 + (l >> 4) * 4;
#pragma unroll
        for (int si = 0; si < 2; ++si) {
            const int w = ws * 32 + si * 16 + (l & 15);
#pragma unroll
            for (int j = 0; j < 4; ++j)
                ob[(size_t)(o0 + j) * 16384 + w] = acc[oi][si][j];
        }
    }
}

// ---------------- fallback fp32 path (round-1, verified) ----------------
#define CB 32
__global__ void fuse_weights_kernel(const float* __restrict__ W,
                                    const float* __restrict__ dw,
                                    const float* __restrict__ P,
                                    float* __restrict__ W2) {
    const int c = blockIdx.x;
    const int o = threadIdx.x;
    float acc[9];
#pragma unroll
    for (int t = 0; t < 9; ++t) acc[t] = 0.f;
    for (int d = 0; d < 128; ++d) {
        const float s = P[o * 128 + d] * dw[d];
        const float* wp = W + (size_t)(d * 128 + c) * 9;
        float tsum = 0.f;
#pragma unroll
        for (int t = 0; t < 9; ++t) {
            const float wv = wp[t];
            acc[t] = fmaf(s, wv, acc[t]);
            tsum += wv;
        }
        acc[0] = fmaf(-s, tsum, acc[0]);
    }
#pragma unroll
    for (int t = 0; t < 9; ++t) W2[(c * 9 + t) * 128 + o] = acc[t];
}

__global__ __launch_bounds__(256) void itpl_conv_kernel(const float* __restrict__ x,
                                                        const float* __restrict__ W2,
                                                        float* __restrict__ out) {
    __shared__ float xs[CB][3][132];
    const int h = blockIdx.x;
    const int n = blockIdx.y;
    const int tid = (int)threadIdx.x;
    const int pg = tid & 15;
    const int og = tid >> 4;
    float acc[8][8];
#pragma unroll
    for (int i = 0; i < 8; ++i)
#pragma unroll
        for (int p = 0; p < 8; ++p) acc[i][p] = 0.f;
    for (int c0 = 0; c0 < 128; c0 += CB) {
        __syncthreads();
        for (int g = tid; g < CB * 3 * 32; g += 256) {
            const int f4 = g & 31;
            const int row = g >> 5;
            const int r = row % 3;
            const int c = row / 3;
            const int hr = h + r - 1;
            float4 v = make_float4(0.f, 0.f, 0.f, 0.f);
            if ((unsigned)hr < 128u)
                v = *reinterpret_cast<const float4*>(
                    x + ((((size_t)n * 128 + c0 + c) * 128 + hr) * 128 + f4 * 4));
            float* dst = &xs[c][r][1 + f4 * 4];
            dst[0] = v.x; dst[1] = v.y; dst[2] = v.z; dst[3] = v.w;
        }
        if (tid < CB * 3) {
            const int r = tid % 3;
            const int c = tid / 3;
            xs[c][r][0] = 0.f;
            xs[c][r][129] = 0.f;
        }
        __syncthreads();
        for (int c = 0; c < CB; ++c) {
#pragma unroll
            for (int kh = 0; kh < 3; ++kh) {
                float xr[12];
                const float* xsp = &xs[c][kh][pg * 8];
                *reinterpret_cast<float4*>(&xr[0]) = *reinterpret_cast<const float4*>(xsp);
                *reinterpret_cast<float4*>(&xr[4]) = *reinterpret_cast<const float4*>(xsp + 4);
                *reinterpret_cast<float4*>(&xr[8]) = *reinterpret_cast<const float4*>(xsp + 8);
#pragma unroll
                for (int kw = 0; kw < 3; ++kw) {
                    const float* wp = W2 + (size_t)((c0 + c) * 9 + kh * 3 + kw) * 128 + og * 8;
                    float wv[8];
                    *reinterpret_cast<float4*>(&wv[0]) = *reinterpret_cast<const float4*>(wp);
                    *reinterpret_cast<float4*>(&wv[4]) = *reinterpret_cast<const float4*>(wp + 4);
#pragma unroll
                    for (int i = 0; i < 8; ++i)
#pragma unroll
                        for (int p = 0; p < 8; ++p)
                            acc[i][p] = fmaf(wv[i], xr[p + kw], acc[i][p]);
                }
            }
        }
    }
#pragma unroll
    for (int i = 0; i < 8; ++i) {
        float* op = out + ((((size_t)n * 128 + og * 8 + i) * 128 + h) * 128 + pg * 8);
        *reinterpret_cast<float4*>(op)     = make_float4(acc[i][0], acc[i][1], acc[i][2], acc[i][3]);
        *reinterpret_cast<float4*>(op + 4) = make_float4(acc[i][4], acc[i][5], acc[i][6], acc[i][7]);
    }
}

extern "C" void kernel_launch(void* const* d_in, const int* in_sizes, int n_in,
                              void* d_out, int out_size, void* d_ws, size_t ws_size,
                              hipStream_t stream) {
    const float* x  = (const float*)d_in[0];
    const float* W  = (const float*)d_in[1];
    const float* dw = (const float*)d_in[2];
    const float* P  = (const float*)d_in[3];
    float* out = (float*)d_out;

    const size_t XB_BYTES = 67108864ull;   // 16*128*128*128 bf16
    const size_t ZR_BYTES = 32768ull;      // one zeroed NHWC row
    const size_t W2B_BYTES = 294912ull;    // 9*16*128*8 bf16
    if (ws_size >= XB_BYTES + ZR_BYTES + W2B_BYTES) {
        unsigned short* xbw  = (unsigned short*)d_ws;
        unsigned short* zrow = (unsigned short*)((char*)d_ws + XB_BYTES);
        unsigned short* w2f  = (unsigned short*)((char*)d_ws + XB_BYTES + ZR_BYTES);
        prep_kernel<<<2176, 256, 0, stream>>>(x, W, dw, P, xbw, zrow, w2f);
        itpl_mfma_kernel<<<2048, 512, 0, stream>>>(xbw, w2f, zrow, out);
    } else {
        float* W2 = (float*)d_ws;
        fuse_weights_kernel<<<128, 128, 0, stream>>>(W, dw, P, W2);
        itpl_conv_kernel<<<dim3(128, 16), 256, 0, stream>>>(x, W2, out);
    }
}